// Round 1
// baseline (463.999 us; speedup 1.0000x reference)
//
#include <hip/hip_runtime.h>
#include <hip/hip_bf16.h>
#include <stdint.h>

#define B_ROWS 4096
#define L_FEAT 256
#define VOCAB  8192

#define BM 128
#define BN 128
#define BK 32

typedef __attribute__((ext_vector_type(8))) short short8;
typedef __attribute__((ext_vector_type(4))) float floatx4;

__device__ __forceinline__ void async_copy16(const void* gsrc, void* ldst) {
  __builtin_amdgcn_global_load_lds(
      (const __attribute__((address_space(1))) void*)gsrc,
      (__attribute__((address_space(3))) void*)ldst, 16, 0, 0);
}

// ---------------- kernel 1: zero the presence matrix -------------------------
__global__ void zero_kernel(uint4* __restrict__ p, int n16) {
  int i = blockIdx.x * blockDim.x + threadIdx.x;
  const int stride = gridDim.x * blockDim.x;
  const uint4 z = make_uint4(0u, 0u, 0u, 0u);
  for (; i < n16; i += stride) p[i] = z;
}

// ---------------- kernel 2: scatter ones -------------------------------------
// Duplicate values in a row write the same 0x3F80 to the same address — benign.
__global__ void scatter_kernel(const int* __restrict__ f,
                               unsigned short* __restrict__ P) {
  const int id  = blockIdx.x * 256 + threadIdx.x;   // exactly B_ROWS*L_FEAT threads
  const int row = id >> 8;                          // L_FEAT == 256
  const int v   = f[id];
  P[(size_t)row * VOCAB + v] = 0x3F80;              // bf16 1.0
}

// ---------------- kernel 3: per-row set sizes --------------------------------
__global__ void sizes_kernel(const uint4* __restrict__ P4,
                             float* __restrict__ sizes) {
  const int row = blockIdx.x;
  const uint4* rp = P4 + (size_t)row * (VOCAB / 8);  // 1024 uint4 per row
  int cnt = 0;
  for (int j = threadIdx.x; j < VOCAB / 8; j += 256) {
    uint4 x = rp[j];
    cnt += ((x.x & 0xFFFFu) ? 1 : 0) + ((x.x >> 16) ? 1 : 0)
         + ((x.y & 0xFFFFu) ? 1 : 0) + ((x.y >> 16) ? 1 : 0)
         + ((x.z & 0xFFFFu) ? 1 : 0) + ((x.z >> 16) ? 1 : 0)
         + ((x.w & 0xFFFFu) ? 1 : 0) + ((x.w >> 16) ? 1 : 0);
  }
  #pragma unroll
  for (int off = 32; off > 0; off >>= 1) cnt += __shfl_down(cnt, off);
  __shared__ int ws[4];
  if ((threadIdx.x & 63) == 0) ws[threadIdx.x >> 6] = cnt;
  __syncthreads();
  if (threadIdx.x == 0)
    sizes[row] = (float)(ws[0] + ws[1] + ws[2] + ws[3]);
}

// ---------------- kernel 4: inter = P·P^T (bf16 MFMA) + Jaccard epilogue -----
// m97 structure: 128x128 tile, BK=32, 4 waves in 2x2, each wave 4x4 of 16x16x32.
// Symmetry: only bx >= by blocks compute (upper triangle of 128-tiles).
__global__ __launch_bounds__(256) void gemm_kernel(
    const unsigned short* __restrict__ P,
    const float* __restrict__ sizes,
    float* __restrict__ out) {
  const int bx = blockIdx.x, by = blockIdx.y;
  if (bx < by) return;  // lower triangle filled by mirror kernel
  const int iBase = by * BM;   // output rows
  const int jBase = bx * BN;   // output cols

  __shared__ __align__(16) unsigned short As[BM * BK];
  __shared__ __align__(16) unsigned short Bs[BN * BK];

  const int tid  = threadIdx.x;
  const int wave = tid >> 6, lane = tid & 63;
  const int wm = wave >> 1, wn = wave & 1;   // 2x2 wave grid, each wave 64x64
  const int col16 = lane & 15, quad = lane >> 4;

  floatx4 acc[4][4];
  #pragma unroll
  for (int a = 0; a < 4; ++a)
    #pragma unroll
    for (int b = 0; b < 4; ++b) acc[a][b] = (floatx4){0.f, 0.f, 0.f, 0.f};

  // staging geometry: one 1024B chunk = 16 rows x 32 cols; lane l -> row l>>2,
  // cols (l&3)*8..+8 so LDS dst = chunk_base + lane*16B (wave-uniform base).
  const int cA   = wave * 2;           // this wave's chunks: cA, cA+1
  const int srow = lane >> 2;          // 0..15
  const int scol = (lane & 3) * 8;     // 0,8,16,24

  for (int k0 = 0; k0 < VOCAB; k0 += BK) {
    __syncthreads();  // protect LDS from overwrite while prior iter still reading
    #pragma unroll
    for (int t = 0; t < 2; ++t) {
      const int c = cA + t;
      const int r = c * 16 + srow;
      const unsigned short* ga = P + (size_t)(iBase + r) * VOCAB + k0 + scol;
      async_copy16(ga, &As[c * 16 * BK]);
      const unsigned short* gb = P + (size_t)(jBase + r) * VOCAB + k0 + scol;
      async_copy16(gb, &Bs[c * 16 * BK]);
    }
    __syncthreads();  // compiler drains vmcnt before s_barrier

    short8 a[4], b[4];
    #pragma unroll
    for (int tm = 0; tm < 4; ++tm)
      a[tm] = *(const short8*)&As[(wm * 64 + tm * 16 + col16) * BK + quad * 8];
    #pragma unroll
    for (int tn = 0; tn < 4; ++tn)
      b[tn] = *(const short8*)&Bs[(wn * 64 + tn * 16 + col16) * BK + quad * 8];
    #pragma unroll
    for (int tm = 0; tm < 4; ++tm)
      #pragma unroll
      for (int tn = 0; tn < 4; ++tn)
        acc[tm][tn] = __builtin_amdgcn_mfma_f32_16x16x32_bf16(
            a[tm], b[tn], acc[tm][tn], 0, 0, 0);
  }

  // epilogue: sim = -inter / (|A_i| + |A_j| - inter)
  #pragma unroll
  for (int tm = 0; tm < 4; ++tm) {
    #pragma unroll
    for (int tn = 0; tn < 4; ++tn) {
      const int col = jBase + wn * 64 + tn * 16 + col16;
      const float sj = sizes[col];
      #pragma unroll
      for (int r = 0; r < 4; ++r) {
        const int row = iBase + wm * 64 + tm * 16 + quad * 4 + r;
        const float inter = acc[tm][tn][r];
        const float u = sizes[row] + sj - inter;
        out[(size_t)row * B_ROWS + col] = (u != 0.f) ? (-inter / u) : 0.f;
      }
    }
  }
}

// ---------------- kernel 5: mirror upper triangle to lower -------------------
__global__ void mirror_kernel(float* __restrict__ out) {
  const int bx = blockIdx.x, by = blockIdx.y;  // 128-tiles
  if (bx >= by) return;                        // only strictly-lower dest tiles
  const int rBase = by * 128, cBase = bx * 128;
  __shared__ float tile[32][33];
  const int tx = threadIdx.x & 31, ty8 = threadIdx.x >> 5;  // 32x8 threads
  for (int s = 0; s < 16; ++s) {
    const int si = s >> 2, sj = s & 3;  // dest 32x32 subtile (si, sj)
    #pragma unroll
    for (int k = 0; k < 4; ++k) {
      const int sr = ty8 + k * 8;
      tile[sr][tx] =
          out[(size_t)(cBase + sj * 32 + sr) * B_ROWS + rBase + si * 32 + tx];
    }
    __syncthreads();
    #pragma unroll
    for (int k = 0; k < 4; ++k) {
      const int dr = ty8 + k * 8;
      out[(size_t)(rBase + si * 32 + dr) * B_ROWS + cBase + sj * 32 + tx] =
          tile[tx][dr];
    }
    __syncthreads();
  }
}

// ---------------- launcher ---------------------------------------------------
extern "C" void kernel_launch(void* const* d_in, const int* in_sizes, int n_in,
                              void* d_out, int out_size, void* d_ws, size_t ws_size,
                              hipStream_t stream) {
  const int* features = (const int*)d_in[0];
  float* out = (float*)d_out;
  unsigned short* P = (unsigned short*)d_ws;                     // 64 MB bf16 presence
  float* sizes = (float*)((char*)d_ws + (size_t)B_ROWS * VOCAB * 2);  // +16 KB

  zero_kernel<<<4096, 256, 0, stream>>>((uint4*)P, B_ROWS * VOCAB * 2 / 16);
  scatter_kernel<<<(B_ROWS * L_FEAT) / 256, 256, 0, stream>>>(features, P);
  sizes_kernel<<<B_ROWS, 256, 0, stream>>>((const uint4*)P, sizes);
  gemm_kernel<<<dim3(32, 32), 256, 0, stream>>>(P, sizes, out);
  mirror_kernel<<<dim3(32, 32), 256, 0, stream>>>(out);
}

// Round 2
// 199.049 us; speedup vs baseline: 2.3311x; 2.3311x over previous
//
#include <hip/hip_runtime.h>
#include <hip/hip_bf16.h>
#include <stdint.h>

#define B_ROWS 4096
#define L_FEAT 256
#define VOCAB  8192

#define BM 128
#define BN 128
#define BK 64   // int8 MFMA K

typedef __attribute__((ext_vector_type(4))) int   intx4;
typedef __attribute__((ext_vector_type(4))) float floatx4;

__device__ __forceinline__ void async_copy16(const void* gsrc, void* ldst) {
  __builtin_amdgcn_global_load_lds(
      (const __attribute__((address_space(1))) void*)gsrc,
      (__attribute__((address_space(3))) void*)ldst, 16, 0, 0);
}

// ---------------- kernel 1: zero the presence matrix (32 MB int8) ------------
__global__ void zero_kernel(uint4* __restrict__ p, int n16) {
  int i = blockIdx.x * blockDim.x + threadIdx.x;
  const int stride = gridDim.x * blockDim.x;
  const uint4 z = make_uint4(0u, 0u, 0u, 0u);
  for (; i < n16; i += stride) p[i] = z;
}

// ---------------- kernel 2: scatter ones (int8) ------------------------------
// Duplicate values in a row write the same 0x01 to the same address — benign.
__global__ void scatter_kernel(const int* __restrict__ f,
                               unsigned char* __restrict__ P) {
  const int id  = blockIdx.x * 256 + threadIdx.x;   // exactly B_ROWS*L_FEAT threads
  const int row = id >> 8;                          // L_FEAT == 256
  const int v   = f[id];
  P[(size_t)row * VOCAB + v] = 1;
}

// ---------------- kernel 3: per-row set sizes --------------------------------
// Bytes are 0x00/0x01 -> popcount of the word == number of set bytes.
__global__ void sizes_kernel(const uint4* __restrict__ P4,
                             float* __restrict__ sizes) {
  const int row = blockIdx.x;
  const uint4* rp = P4 + (size_t)row * (VOCAB / 16);  // 512 uint4 per row
  int cnt = 0;
  for (int j = threadIdx.x; j < VOCAB / 16; j += 256) {
    uint4 x = rp[j];
    cnt += __popc(x.x) + __popc(x.y) + __popc(x.z) + __popc(x.w);
  }
  #pragma unroll
  for (int off = 32; off > 0; off >>= 1) cnt += __shfl_down(cnt, off);
  __shared__ int ws[4];
  if ((threadIdx.x & 63) == 0) ws[threadIdx.x >> 6] = cnt;
  __syncthreads();
  if (threadIdx.x == 0)
    sizes[row] = (float)(ws[0] + ws[1] + ws[2] + ws[3]);
}

// ---------------- kernel 4: inter = P·P^T (i8 MFMA) + Jaccard epilogue -------
// 128x128 tile, BK=64, 4 waves in 2x2, each wave 4x4 of mfma_i32_16x16x64_i8.
// 1-D triangle grid: only bx >= by tiles are launched.
__global__ __launch_bounds__(256) void gemm_kernel(
    const unsigned char* __restrict__ P,
    const float* __restrict__ sizes,
    float* __restrict__ out) {
  // decode linear triangle index -> (by, bx) with bx >= by (row-major triangle)
  int b = blockIdx.x, by = 0, rem = 32;
  while (b >= rem) { b -= rem; ++by; --rem; }
  const int bx = by + b;
  const int iBase = by * BM;   // output rows
  const int jBase = bx * BN;   // output cols

  __shared__ __align__(16) unsigned char As[BM * BK];  // 8 KB
  __shared__ __align__(16) unsigned char Bs[BN * BK];  // 8 KB

  const int tid  = threadIdx.x;
  const int wave = tid >> 6, lane = tid & 63;
  const int wm = wave >> 1, wn = wave & 1;   // 2x2 wave grid, each wave 64x64
  const int col16 = lane & 15, quad = lane >> 4;

  intx4 acc[4][4];
  #pragma unroll
  for (int a = 0; a < 4; ++a)
    #pragma unroll
    for (int c = 0; c < 4; ++c) acc[a][c] = (intx4){0, 0, 0, 0};

  // staging: chunk = 16 rows x 64 cols = 1 KB; lane l -> row l>>2, col (l&3)*16
  // so LDS dst = chunk_base + lane*16 (wave-uniform base, contiguous). 8 chunks
  // per matrix per k-iter; wave w does chunks {w, w+4} for A and B.
  const int srow = lane >> 2;          // 0..15
  const int scol = (lane & 3) * 16;    // 0,16,32,48

  for (int k0 = 0; k0 < VOCAB; k0 += BK) {
    __syncthreads();  // protect LDS from overwrite while prior iter still reading
    #pragma unroll
    for (int t = 0; t < 2; ++t) {
      const int c = wave + t * 4;          // chunk 0..7
      const int r = c * 16 + srow;         // tile row 0..127
      async_copy16(P + (size_t)(iBase + r) * VOCAB + k0 + scol, &As[c * 1024]);
      async_copy16(P + (size_t)(jBase + r) * VOCAB + k0 + scol, &Bs[c * 1024]);
    }
    __syncthreads();  // compiler drains vmcnt before s_barrier

    intx4 a[4], bfr[4];
    #pragma unroll
    for (int tm = 0; tm < 4; ++tm)
      a[tm] = *(const intx4*)&As[(wm * 64 + tm * 16 + col16) * BK + quad * 16];
    #pragma unroll
    for (int tn = 0; tn < 4; ++tn)
      bfr[tn] = *(const intx4*)&Bs[(wn * 64 + tn * 16 + col16) * BK + quad * 16];
    #pragma unroll
    for (int tm = 0; tm < 4; ++tm)
      #pragma unroll
      for (int tn = 0; tn < 4; ++tn)
        acc[tm][tn] = __builtin_amdgcn_mfma_i32_16x16x64_i8(
            a[tm], bfr[tn], acc[tm][tn], 0, 0, 0);
  }

  // epilogue: sim = -inter / (|A_i| + |A_j| - inter)
  #pragma unroll
  for (int tm = 0; tm < 4; ++tm) {
    #pragma unroll
    for (int tn = 0; tn < 4; ++tn) {
      const int col = jBase + wn * 64 + tn * 16 + col16;
      const float sj = sizes[col];
      #pragma unroll
      for (int r = 0; r < 4; ++r) {
        const int row = iBase + wm * 64 + tm * 16 + quad * 4 + r;
        const float inter = (float)acc[tm][tn][r];
        const float u = sizes[row] + sj - inter;
        out[(size_t)row * B_ROWS + col] = (u != 0.f) ? (-inter / u) : 0.f;
      }
    }
  }
}

// ---------------- kernel 5: mirror upper triangle to lower -------------------
__global__ void mirror_kernel(float* __restrict__ out) {
  const int bx = blockIdx.x, by = blockIdx.y;  // 128-tiles
  if (bx >= by) return;                        // only strictly-lower dest tiles
  const int rBase = by * 128, cBase = bx * 128;
  __shared__ float tile[32][33];
  const int tx = threadIdx.x & 31, ty8 = threadIdx.x >> 5;  // 32x8 threads
  for (int s = 0; s < 16; ++s) {
    const int si = s >> 2, sj = s & 3;  // dest 32x32 subtile (si, sj)
    #pragma unroll
    for (int k = 0; k < 4; ++k) {
      const int sr = ty8 + k * 8;
      tile[sr][tx] =
          out[(size_t)(cBase + sj * 32 + sr) * B_ROWS + rBase + si * 32 + tx];
    }
    __syncthreads();
    #pragma unroll
    for (int k = 0; k < 4; ++k) {
      const int dr = ty8 + k * 8;
      out[(size_t)(rBase + si * 32 + dr) * B_ROWS + cBase + sj * 32 + tx] =
          tile[tx][dr];
    }
    __syncthreads();
  }
}

// ---------------- launcher ---------------------------------------------------
extern "C" void kernel_launch(void* const* d_in, const int* in_sizes, int n_in,
                              void* d_out, int out_size, void* d_ws, size_t ws_size,
                              hipStream_t stream) {
  const int* features = (const int*)d_in[0];
  float* out = (float*)d_out;
  unsigned char* P = (unsigned char*)d_ws;                    // 32 MB int8 presence
  float* sizes = (float*)((char*)d_ws + (size_t)B_ROWS * VOCAB);  // +16 KB

  zero_kernel<<<2048, 256, 0, stream>>>((uint4*)P, B_ROWS * VOCAB / 16);
  scatter_kernel<<<(B_ROWS * L_FEAT) / 256, 256, 0, stream>>>(features, P);
  sizes_kernel<<<B_ROWS, 256, 0, stream>>>((const uint4*)P, sizes);
  gemm_kernel<<<528, 256, 0, stream>>>(P, sizes, out);
  mirror_kernel<<<dim3(32, 32), 256, 0, stream>>>(out);
}